// Round 3
// baseline (1515.582 us; speedup 1.0000x reference)
//
#include <hip/hip_runtime.h>

typedef __attribute__((ext_vector_type(8))) short short8;   // 8 bf16 = 4 VGPRs (MFMA A/B frag)
typedef __attribute__((ext_vector_type(4))) float f32x4;    // MFMA C/D frag

#define F    256
#define SH   264     // LDS row stride in bf16 units: 528 B, 8B-aligned, <=2-way bank aliasing
#define ROWS 128     // rows per block

__device__ __forceinline__ short f2bf(float f) {
    union { float f; unsigned u; } v; v.f = f;
    unsigned r = (v.u + 0x7fffu + ((v.u >> 16) & 1u)) >> 16;   // RTNE
    return (short)r;
}
__device__ __forceinline__ float bf2f(short s) {
    union { float f; unsigned u; } v; v.u = ((unsigned)(unsigned short)s) << 16;
    return v.f;
}
__device__ __forceinline__ float sigm(float x) {
    return __builtin_amdgcn_rcpf(1.f + __builtin_amdgcn_exp2f(-1.442695041f * x));
}
__device__ __forceinline__ float tanhx(float x) {
    return 1.f - 2.f * __builtin_amdgcn_rcpf(1.f + __builtin_amdgcn_exp2f(2.885390082f * x));
}
__device__ __forceinline__ f32x4 splat4(float v) {
    f32x4 r; r[0] = v; r[1] = v; r[2] = v; r[3] = v; return r;
}

// ---------------------------------------------------------------------------
// Pack: swizzle W_hh, W_ih (hi+lo split), W_out into MFMA-B-fragment order,
// BLOCK-SLICED: col-block c's 8 n-tiles are one contiguous 64 KB slice.
// whh/wih: dst = c*32768 + ((i*8 + kt)*512 + lane*8), i = 2*gate + s,
// where global n-tile nt -> gate = nt>>4, s = nt&1, c = (nt&15)>>1.
// wout: dst = c*8192 + (((s)*8 + kt)*512 + lane*8), nt = 2c + s.
// Also zeroes the per-row-group exchange counters (monotonic).
// ---------------------------------------------------------------------------
__global__ void pack_kernel(const float* __restrict__ Whh, const float* __restrict__ Wih,
                            const float* __restrict__ Wout,
                            short* __restrict__ whh_p, short* __restrict__ wih_hi,
                            short* __restrict__ wih_lo, short* __restrict__ wout_p,
                            unsigned* __restrict__ ctr)
{
    int idx = blockIdx.x * blockDim.x + threadIdx.x;
    if (idx < 64) ctr[idx] = 0u;
    if (idx < 64 * 8 * 64) {                       // W_hh + W_ih: 64 n-tiles x 8 kt x 64 lanes
        int lane = idx & 63, kt = (idx >> 6) & 7, nt = idx >> 9;
        int n = nt * 16 + (lane & 15);             // gate-row 0..1023
        int k = kt * 32 + (lane >> 4) * 8;
        int c = (nt & 15) >> 1;
        int i = ((nt >> 4) << 1) | (nt & 1);       // 2*gate + s
        int dst = c * 32768 + ((i * 8 + kt) * 512 + lane * 8);
        const float* s1 = Whh + n * F + k;
        const float* s2 = Wih + n * F + k;
        #pragma unroll
        for (int j = 0; j < 8; j++) {
            whh_p[dst + j] = f2bf(s1[j]);
            float v = s2[j];
            short hi = f2bf(v);
            wih_hi[dst + j] = hi;
            wih_lo[dst + j] = f2bf(v - bf2f(hi));
        }
    } else {
        int i2 = idx - 64 * 8 * 64;
        if (i2 < 16 * 8 * 64) {                    // W_out: 16 n-tiles
            int lane = i2 & 63, kt = (i2 >> 6) & 7, nt = i2 >> 9;
            int n = nt * 16 + (lane & 15);
            int k = kt * 32 + (lane >> 4) * 8;
            int c = nt >> 1, s = nt & 1;
            int dst = c * 8192 + ((s * 8 + kt) * 512 + lane * 8);
            const float* sp = Wout + n * F + k;
            #pragma unroll
            for (int j = 0; j < 8; j++) wout_p[dst + j] = f2bf(sp[j]);
        }
    }
}

// Load a wave's 32 B-fragments (4 gates x 8 kt, its cw half) into registers.
__device__ __forceinline__ void load_wb(short8 (&wb)[4][8], const short* __restrict__ base,
                                        int cw, int lane)
{
    #pragma unroll
    for (int g = 0; g < 4; g++)
        #pragma unroll
        for (int kt = 0; kt < 8; kt++)
            wb[g][kt] = *(const short8*)(base + (((2 * g + cw) * 8 + kt) * 512 + lane * 8));
}

// acc[g][mt] += A(rows rw*32 + mt*16, from LDS) x wb[g][kt] over K=256.
__device__ __forceinline__ void mm_reg(f32x4 (&acc)[4][2], const short8 (&wb)[4][8],
                                       const short* hb, int rw, int l15, int quad)
{
    #pragma unroll
    for (int kt = 0; kt < 8; kt++) {
        short8 a0 = *(const short8*)(hb + (rw * 32 + l15) * SH + kt * 32 + quad * 8);
        short8 a1 = *(const short8*)(hb + (rw * 32 + 16 + l15) * SH + kt * 32 + quad * 8);
        #pragma unroll
        for (int g = 0; g < 4; g++) {
            acc[g][0] = __builtin_amdgcn_mfma_f32_16x16x32_bf16(a0, wb[g][kt], acc[g][0], 0, 0, 0);
            acc[g][1] = __builtin_amdgcn_mfma_f32_16x16x32_bf16(a1, wb[g][kt], acc[g][1], 0, 0, 0);
        }
    }
}

// ---------------------------------------------------------------------------
// Weights-stationary fused LSTM.  256 blocks (1/CU, all co-resident) =
// 32 row-groups x 8 col-blocks.  Block (rg,c): 128 rows x 32 h-cols.
// W_hh slice lives in REGISTERS (32 frags/wave) for all T steps; W_out slice
// in LDS.  Per step the 8 col-blocks of a row-group exchange h chunks via an
// LLC-coherent double-buffered global buffer (relaxed agent atomics) + one
// monotonic release/acquire counter per group.  No weight re-streaming.
// ---------------------------------------------------------------------------
__global__ __launch_bounds__(512, 2)
void lstm_fused(const float* __restrict__ x, const float* __restrict__ b_ih,
                const float* __restrict__ b_hh, const float* __restrict__ c0,
                const float* __restrict__ b_out,
                const short* __restrict__ whh_p, const short* __restrict__ wih_hi,
                const short* __restrict__ wih_lo, const short* __restrict__ wout_p,
                const int* __restrict__ seqlen, unsigned* __restrict__ ctr,
                unsigned short* __restrict__ G, float* __restrict__ out)
{
    __shared__ short hbuf[ROWS * SH];      // 67.6 KB
    __shared__ short wlout[8192];          // 16.4 KB   (total 84 KB -> 1 block/CU)
    const int T    = *seqlen;
    const int tid  = threadIdx.x;
    const int lane = tid & 63;
    const int wv   = tid >> 6;             // wave 0..7
    const int rw   = wv >> 1;              // row-wave 0..3  (32 rows each)
    const int cw   = wv & 1;               // col-wave 0..1  (16 h-cols each)
    const int l15  = lane & 15;
    const int quad = lane >> 4;
    const int c    = blockIdx.x & 7;       // col-block 0..7
    const int rg   = blockIdx.x >> 3;      // row-group 0..31
    const int row0 = rg * ROWS;

    // ---- stage W_out slice -> LDS (16 shorts/thread, own region) ----
    {
        const short* src = wout_p + c * 8192;
        #pragma unroll
        for (int j = 0; j < 2; j++)
            *(short8*)(wlout + tid * 16 + j * 8) = *(const short8*)(src + tid * 16 + j * 8);
    }

    // staging geometry: thread covers row xr, 64 cols in 16 chunks of 4 (bank-spread)
    const int xr  = tid >> 2;              // 0..127
    const int xq  = (tid & 3) * 4;         // col chunk base (elements)

    // ---- x_proj = x @ W_ih^T (+biases), fp32-exact via 3-term split bf16 ----
    f32x4 xpj[4][2];
    #pragma unroll
    for (int g = 0; g < 4; g++) { xpj[g][0] = splat4(0.f); xpj[g][1] = splat4(0.f); }

    short8 wb[4][8];

    // stage x_lo
    {
        const float* xp = x + (size_t)(row0 + xr) * F;
        #pragma unroll
        for (int j = 0; j < 16; j++) {
            f32x4 v = *(const f32x4*)(xp + xq + j * 16);
            #pragma unroll
            for (int e = 0; e < 4; e++) {
                short hi = f2bf(v[e]);
                hbuf[xr * SH + xq + j * 16 + e] = f2bf(v[e] - bf2f(hi));
            }
        }
    }
    load_wb(wb, wih_hi + c * 32768, cw, lane);
    __syncthreads();
    mm_reg(xpj, wb, hbuf, rw, l15, quad);          // x_lo x Wih_hi
    __syncthreads();
    // stage x_hi (stays as h_0)
    {
        const float* xp = x + (size_t)(row0 + xr) * F;
        #pragma unroll
        for (int j = 0; j < 16; j++) {
            f32x4 v = *(const f32x4*)(xp + xq + j * 16);
            #pragma unroll
            for (int e = 0; e < 4; e++)
                hbuf[xr * SH + xq + j * 16 + e] = f2bf(v[e]);
        }
    }
    __syncthreads();
    mm_reg(xpj, wb, hbuf, rw, l15, quad);          // x_hi x Wih_hi
    load_wb(wb, wih_lo + c * 32768, cw, lane);
    mm_reg(xpj, wb, hbuf, rw, l15, quad);          // x_hi x Wih_lo
    load_wb(wb, whh_p + c * 32768, cw, lane);      // persistent W_hh frags

    // biases (b_ih + b_hh) per gate column
    const int mycol = c * 32 + cw * 16 + l15;      // this lane's h-col / out-col
    #pragma unroll
    for (int g = 0; g < 4; g++) {
        float bias = b_ih[g * 256 + mycol] + b_hh[g * 256 + mycol];
        #pragma unroll
        for (int mt = 0; mt < 2; mt++)
            #pragma unroll
            for (int r = 0; r < 4; r++) xpj[g][mt][r] += bias;
    }

    // cell state init + output bias
    float cst[2][4];
    const float bo = b_out[mycol];
    {
        float cv = c0[mycol];
        #pragma unroll
        for (int mt = 0; mt < 2; mt++)
            #pragma unroll
            for (int r = 0; r < 4; r++) cst[mt][r] = cv;
    }

    const size_t orow = (size_t)T * F;

    for (int t = 0; t < T; t++) {
        // gates = x_proj + h_t @ W_hh^T   (B-frags from registers, A from LDS)
        f32x4 acc[4][2];
        #pragma unroll
        for (int g = 0; g < 4; g++) { acc[g][0] = xpj[g][0]; acc[g][1] = xpj[g][1]; }
        mm_reg(acc, wb, hbuf, rw, l15, quad);

        // in-register cell update; own h-chunk -> exchange buffer (LLC-coherent)
        unsigned short* Gw = G + (((size_t)(t + 1) & 1) << 20);   // 4096*256
        #pragma unroll
        for (int mt = 0; mt < 2; mt++)
          #pragma unroll
          for (int r = 0; r < 4; r++) {
            float ig = sigm(acc[0][mt][r]);
            float fg = sigm(acc[1][mt][r]);
            float gg = tanhx(acc[2][mt][r]);
            float og = sigm(acc[3][mt][r]);
            float cn = fg * cst[mt][r] + ig * gg;
            cst[mt][r] = cn;
            unsigned short hb16 = (unsigned short)f2bf(og * tanhx(cn));
            int grow = row0 + rw * 32 + mt * 16 + quad * 4 + r;
            __hip_atomic_store(&Gw[(size_t)grow * 256 + mycol], hb16,
                               __ATOMIC_RELAXED, __HIP_MEMORY_SCOPE_AGENT);
          }

        __syncthreads();   // drains all waves' h stores; all done reading hbuf

        // group barrier: 8 col-blocks of this row-group (monotonic, bounded)
        if (tid == 0) {
            __hip_atomic_fetch_add(&ctr[rg], 1u, __ATOMIC_RELEASE,
                                   __HIP_MEMORY_SCOPE_AGENT);
            unsigned tgt = 8u * (unsigned)(t + 1);
            int guard = 0;
            while (__hip_atomic_load(&ctr[rg], __ATOMIC_RELAXED,
                                     __HIP_MEMORY_SCOPE_AGENT) < tgt
                   && guard < (1 << 20)) {
                __builtin_amdgcn_s_sleep(1); guard++;
            }
            (void)__hip_atomic_load(&ctr[rg], __ATOMIC_ACQUIRE,
                                    __HIP_MEMORY_SCOPE_AGENT);
        }
        __syncthreads();

        // stage h_{t+1}[row-group, all 256 cols] -> hbuf (serves out-proj AND next step)
        {
            const unsigned short* gp = Gw + (size_t)(row0 + xr) * 256;
            #pragma unroll
            for (int j = 0; j < 16; j++) {
                unsigned long long v = __hip_atomic_load(
                    (const unsigned long long*)(gp + xq + j * 16),
                    __ATOMIC_RELAXED, __HIP_MEMORY_SCOPE_AGENT);
                *(unsigned long long*)(hbuf + xr * SH + xq + j * 16) = v;
            }
        }
        __syncthreads();

        // fused output projection (hs[t] = h_{t+1}): out = h @ W_out^T + b_out
        f32x4 oacc[2];
        oacc[0] = splat4(bo); oacc[1] = splat4(bo);
        #pragma unroll
        for (int kt = 0; kt < 8; kt++) {
            short8 a0 = *(const short8*)(hbuf + (rw * 32 + l15) * SH + kt * 32 + quad * 8);
            short8 a1 = *(const short8*)(hbuf + (rw * 32 + 16 + l15) * SH + kt * 32 + quad * 8);
            short8 b  = *(const short8*)(wlout + (cw * 8 + kt) * 512 + lane * 8);
            oacc[0] = __builtin_amdgcn_mfma_f32_16x16x32_bf16(a0, b, oacc[0], 0, 0, 0);
            oacc[1] = __builtin_amdgcn_mfma_f32_16x16x32_bf16(a1, b, oacc[1], 0, 0, 0);
        }
        #pragma unroll
        for (int mt = 0; mt < 2; mt++)
          #pragma unroll
          for (int r = 0; r < 4; r++) {
            size_t row = (size_t)(row0 + rw * 32 + mt * 16 + quad * 4 + r);
            __builtin_nontemporal_store(oacc[mt][r],
                out + row * orow + (size_t)t * F + mycol);
          }
    }
}

extern "C" void kernel_launch(void* const* d_in, const int* in_sizes, int n_in,
                              void* d_out, int out_size, void* d_ws, size_t ws_size,
                              hipStream_t stream)
{
    const float* x    = (const float*)d_in[0];
    const float* Wih  = (const float*)d_in[1];
    const float* Whh  = (const float*)d_in[2];
    const float* bih  = (const float*)d_in[3];
    const float* bhh  = (const float*)d_in[4];
    const float* c0   = (const float*)d_in[5];
    const float* Wout = (const float*)d_in[6];
    const float* bout = (const float*)d_in[7];
    const int* seqlen = (const int*)d_in[8];

    // workspace layout (bytes): packed weights, counters, h exchange buffers
    char* ws = (char*)d_ws;
    short* whh_p  = (short*)(ws);                       // 512 KB
    short* wih_hi = (short*)(ws + 512 * 1024);          // 512 KB
    short* wih_lo = (short*)(ws + 1024 * 1024);         // 512 KB
    short* wout_p = (short*)(ws + 1536 * 1024);         // 128 KB
    unsigned* ctr = (unsigned*)(ws + 1664 * 1024);      // 256 B (64 counters)
    unsigned short* G = (unsigned short*)(ws + 2048 * 1024);  // 2 x 2 MB h buffers
    (void)ws_size; (void)in_sizes; (void)n_in; (void)out_size;

    pack_kernel<<<160, 256, 0, stream>>>(Whh, Wih, Wout, whh_p, wih_hi, wih_lo,
                                         wout_p, ctr);
    lstm_fused<<<256, 512, 0, stream>>>(x, bih, bhh, c0, bout,
                                        whh_p, wih_hi, wih_lo, wout_p,
                                        seqlen, ctr, G, (float*)d_out);
}

// Round 5
// 1030.866 us; speedup vs baseline: 1.4702x; 1.4702x over previous
//
#include <hip/hip_runtime.h>

typedef __attribute__((ext_vector_type(8))) short short8;   // 8 bf16 = 4 VGPRs (MFMA A/B frag)
typedef __attribute__((ext_vector_type(4))) float f32x4;    // MFMA C/D frag

#define F   256
#define SH  264   // LDS row stride in bf16 units: 528 B, 16B-aligned, <=2-way bank aliasing

__device__ __forceinline__ short f2bf(float f) {
    union { float f; unsigned u; } v; v.f = f;
    unsigned r = (v.u + 0x7fffu + ((v.u >> 16) & 1u)) >> 16;   // RTNE
    return (short)r;
}
__device__ __forceinline__ float bf2f(short s) {
    union { float f; unsigned u; } v; v.u = ((unsigned)(unsigned short)s) << 16;
    return v.f;
}
__device__ __forceinline__ float sigm(float x) {
    return __builtin_amdgcn_rcpf(1.f + __builtin_amdgcn_exp2f(-1.442695041f * x));
}
__device__ __forceinline__ float tanhx(float x) {
    return 1.f - 2.f * __builtin_amdgcn_rcpf(1.f + __builtin_amdgcn_exp2f(2.885390082f * x));
}
__device__ __forceinline__ f32x4 splat4(float v) {
    f32x4 r; r[0] = v; r[1] = v; r[2] = v; r[3] = v; return r;
}

// ---------------------------------------------------------------------------
// Pack kernel (R1 layout): W_hh, W_ih (hi+lo split), W_out in MFMA-B-fragment
// order, WAVE-CONTIGUOUS: whh/wih dst = ((w*8+kt)*8 + i)*512 + lane*8 with
// nt = (i>>1)*16 + 2w + (i&1).  wout dst = ((w*8+kt)*2 + s)*512 + lane*8,
// nt = 2w + s.
// ---------------------------------------------------------------------------
__global__ void pack_kernel(const float* __restrict__ Whh, const float* __restrict__ Wih,
                            const float* __restrict__ Wout,
                            short* __restrict__ whh_p, short* __restrict__ wih_hi,
                            short* __restrict__ wih_lo, short* __restrict__ wout_p)
{
    int idx = blockIdx.x * blockDim.x + threadIdx.x;
    if (idx < 64 * 8 * 64) {                       // W_hh + W_ih: 64 n-tiles x 8 kt x 64 lanes
        int lane = idx & 63, kt = (idx >> 6) & 7, nt = idx >> 9;
        int n = nt * 16 + (lane & 15);
        int k = kt * 32 + (lane >> 4) * 8;
        int w = (nt & 15) >> 1;
        int i = ((nt >> 4) << 1) | (nt & 1);
        int dst = (((w * 8 + kt) * 8 + i) * 64 + lane) * 8;
        const float* s1 = Whh + n * F + k;
        const float* s2 = Wih + n * F + k;
        #pragma unroll
        for (int j = 0; j < 8; j++) {
            whh_p[dst + j] = f2bf(s1[j]);
            float v = s2[j];
            short hi = f2bf(v);
            wih_hi[dst + j] = hi;
            wih_lo[dst + j] = f2bf(v - bf2f(hi));
        }
    } else {
        int i2 = idx - 64 * 8 * 64;
        if (i2 < 16 * 8 * 64) {                    // W_out: 16 n-tiles
            int lane = i2 & 63, kt = (i2 >> 6) & 7, nt = i2 >> 9;
            int n = nt * 16 + (lane & 15);
            int k = kt * 32 + (lane >> 4) * 8;
            int w = nt >> 1, s = nt & 1;
            int dst = (((w * 8 + kt) * 2 + s) * 64 + lane) * 8;
            const float* sp = Wout + n * F + k;
            #pragma unroll
            for (int j = 0; j < 8; j++) wout_p[dst + j] = f2bf(sp[j]);
        }
    }
}

// Accumulate acc[i][mt] += A(h in LDS) x B(packed W, wave-contiguous).
// Wp pre-offset to the wave's 32768-short slice.  Depth-1.5 software pipeline.
__device__ __forceinline__ void gate_mm(f32x4 (&acc)[8][2], const short* __restrict__ Wp,
                                        const short* hb, int lane)
{
    const int l15 = lane & 15, quad = lane >> 4;
    const short* bp = Wp + lane * 8;
    short8 be[8], bod[8];
    #pragma unroll
    for (int i = 0; i < 8; i++) be[i] = *(const short8*)(bp + i * 512);     // kt=0
    #pragma unroll
    for (int kt = 0; kt < 8; kt += 2) {
        #pragma unroll
        for (int i = 0; i < 8; i++)
            bod[i] = *(const short8*)(bp + (kt + 1) * 4096 + i * 512);
        short8 a0 = *(const short8*)(hb + l15 * SH + kt * 32 + quad * 8);
        short8 a1 = *(const short8*)(hb + (16 + l15) * SH + kt * 32 + quad * 8);
        #pragma unroll
        for (int i = 0; i < 8; i++) {
            acc[i][0] = __builtin_amdgcn_mfma_f32_16x16x32_bf16(a0, be[i], acc[i][0], 0, 0, 0);
            acc[i][1] = __builtin_amdgcn_mfma_f32_16x16x32_bf16(a1, be[i], acc[i][1], 0, 0, 0);
        }
        if (kt + 2 < 8) {
            #pragma unroll
            for (int i = 0; i < 8; i++)
                be[i] = *(const short8*)(bp + (kt + 2) * 4096 + i * 512);
        }
        a0 = *(const short8*)(hb + l15 * SH + (kt + 1) * 32 + quad * 8);
        a1 = *(const short8*)(hb + (16 + l15) * SH + (kt + 1) * 32 + quad * 8);
        #pragma unroll
        for (int i = 0; i < 8; i++) {
            acc[i][0] = __builtin_amdgcn_mfma_f32_16x16x32_bf16(a0, bod[i], acc[i][0], 0, 0, 0);
            acc[i][1] = __builtin_amdgcn_mfma_f32_16x16x32_bf16(a1, bod[i], acc[i][1], 0, 0, 0);
        }
    }
}

// ---------------------------------------------------------------------------
// Recurrence kernel.  128 blocks x 512 threads (8 waves); block owns 32 rows
// for all T steps.  MODE 0: dump h (bf16, full-line NT) to G each step;
// out-projection deferred to out_proj kernel.  MODE 1: R1 fused fallback
// (wout in LDS, fp32 out stores) if workspace can't hold G.
// ---------------------------------------------------------------------------
template<int FUSED>
__global__ __launch_bounds__(512, 2)
void lstm_ker(const float* __restrict__ x, const float* __restrict__ b_ih,
              const float* __restrict__ b_hh, const float* __restrict__ c0,
              const float* __restrict__ b_out,
              const short* __restrict__ whh_p, const short* __restrict__ wih_hi,
              const short* __restrict__ wih_lo, const short* __restrict__ wout_p,
              const int* __restrict__ seqlen, short* __restrict__ G,
              float* __restrict__ out)
{
    __shared__ short hbuf[32 * SH];                   // 16.9 KB
    __shared__ short wout_lds[FUSED ? 65536 : 8];     // 128 KB only in fused mode
    const int T    = *seqlen;
    const int tid  = threadIdx.x;
    const int lane = tid & 63;
    const int w    = tid >> 6;        // wave 0..7
    const int l15  = lane & 15;
    const int quad = lane >> 4;
    const int row0 = blockIdx.x * 32;

    const short* whh_w    = whh_p  + (w << 15);   // per-wave 32768-short slice
    const short* wih_hi_w = wih_hi + (w << 15);
    const short* wih_lo_w = wih_lo + (w << 15);

    if (FUSED) {   // stage wave's W_out slice -> LDS (own region: no barrier)
        const short* src = wout_p + w * 8192 + lane * 8;
        short*       dst = wout_lds + w * 8192 + lane * 8;
        #pragma unroll
        for (int q = 0; q < 16; q++)
            *(short8*)(dst + q * 512) = *(const short8*)(src + q * 512);
    }

    // ---- load this block's 32 x-rows (fp32, coalesced dwordx4) ----
    const int xr = tid >> 4;          // 0..31
    const int xc = (tid & 15) * 16;   // 0..240
    float xv[16];
    {
        const float* xp = x + (size_t)(row0 + xr) * F + xc;
        #pragma unroll
        for (int j = 0; j < 16; j++) xv[j] = xp[j];
    }

    // ---- x_proj = x @ W_ih^T + b_ih + b_hh, fp32-accurate via 3-term split bf16 ----
    f32x4 xpj[8][2];
    #pragma unroll
    for (int i = 0; i < 8; i++) { xpj[i][0] = splat4(0.f); xpj[i][1] = splat4(0.f); }

    #pragma unroll
    for (int j = 0; j < 16; j++) {
        short hi = f2bf(xv[j]);
        hbuf[xr * SH + xc + j] = f2bf(xv[j] - bf2f(hi));
    }
    __syncthreads();
    gate_mm(xpj, wih_hi_w, hbuf, lane);              // x_lo x Wih_hi
    __syncthreads();
    #pragma unroll
    for (int j = 0; j < 16; j++) hbuf[xr * SH + xc + j] = f2bf(xv[j]);
    __syncthreads();
    gate_mm(xpj, wih_hi_w, hbuf, lane);              // x_hi x Wih_hi
    gate_mm(xpj, wih_lo_w, hbuf, lane);              // x_hi x Wih_lo

    // biases (b_ih + b_hh), per-gate column
    #pragma unroll
    for (int i = 0; i < 8; i++) {
        int nt = (i >> 1) * 16 + 2 * w + (i & 1);
        float bias = b_ih[nt * 16 + l15] + b_hh[nt * 16 + l15];
        #pragma unroll
        for (int mt = 0; mt < 2; mt++)
            #pragma unroll
            for (int r = 0; r < 4; r++) xpj[i][mt][r] += bias;
    }

    // cell state init (c0 broadcast over rows) + output bias
    float cst[2][2][4];
    float bo[2];
    #pragma unroll
    for (int s = 0; s < 2; s++) {
        float cv = c0[w * 32 + s * 16 + l15];
        bo[s]    = b_out[w * 32 + s * 16 + l15];
        #pragma unroll
        for (int mt = 0; mt < 2; mt++)
            #pragma unroll
            for (int r = 0; r < 4; r++) cst[s][mt][r] = cv;
    }

    const size_t orow = (size_t)T * F;
    const short* wl = wout_lds + w * 8192 + lane * 8;
    const int dxc = (tid & 15) * 8;   // dump geometry: 16 lanes x 16B contiguous

    for (int t = 0; t < T; t++) {
        // gates = x_proj + h_t @ W_hh^T
        f32x4 acc[8][2];
        #pragma unroll
        for (int i = 0; i < 8; i++) { acc[i][0] = xpj[i][0]; acc[i][1] = xpj[i][1]; }
        gate_mm(acc, whh_w, hbuf, lane);

        __syncthreads();   // all waves done reading h_t from LDS

        // in-register LSTM cell update (fp32), h -> LDS bf16
        #pragma unroll
        for (int s = 0; s < 2; s++)
          #pragma unroll
          for (int mt = 0; mt < 2; mt++)
            #pragma unroll
            for (int r = 0; r < 4; r++) {
                float ig = sigm(acc[0 + s][mt][r]);
                float fg = sigm(acc[2 + s][mt][r]);
                float gg = tanhx(acc[4 + s][mt][r]);
                float og = sigm(acc[6 + s][mt][r]);
                float c  = fg * cst[s][mt][r] + ig * gg;
                cst[s][mt][r] = c;
                hbuf[(mt * 16 + quad * 4 + r) * SH + w * 32 + s * 16 + l15]
                    = f2bf(og * tanhx(c));
            }
        __syncthreads();   // h_{t+1} visible to all waves

        if (!FUSED) {
            // dump h_{t+1} -> G[(row*T + t)*256 + col], bf16 NT, full-line
            short* gp = G + ((size_t)(row0 + xr) * T + t) * F;
            short8 h0 = *(const short8*)(hbuf + xr * SH + dxc);
            short8 h1 = *(const short8*)(hbuf + xr * SH + 128 + dxc);
            __builtin_nontemporal_store(h0, (short8*)(gp + dxc));
            __builtin_nontemporal_store(h1, (short8*)(gp + 128 + dxc));
        } else {
            // fused output projection from LDS-resident W_out (R1 path)
            f32x4 oacc[2][2];
            #pragma unroll
            for (int s = 0; s < 2; s++) { oacc[s][0] = splat4(bo[s]); oacc[s][1] = splat4(bo[s]); }
            #pragma unroll
            for (int kt = 0; kt < 8; kt++) {
                short8 a0 = *(const short8*)(hbuf + l15 * SH + kt * 32 + quad * 8);
                short8 a1 = *(const short8*)(hbuf + (16 + l15) * SH + kt * 32 + quad * 8);
                #pragma unroll
                for (int s = 0; s < 2; s++) {
                    short8 b = *(const short8*)(wl + kt * 1024 + s * 512);
                    oacc[s][0] = __builtin_amdgcn_mfma_f32_16x16x32_bf16(a0, b, oacc[s][0], 0, 0, 0);
                    oacc[s][1] = __builtin_amdgcn_mfma_f32_16x16x32_bf16(a1, b, oacc[s][1], 0, 0, 0);
                }
            }
            float* op = out + (size_t)row0 * orow + (size_t)t * F;
            #pragma unroll
            for (int s = 0; s < 2; s++)
              #pragma unroll
              for (int mt = 0; mt < 2; mt++)
                #pragma unroll
                for (int r = 0; r < 4; r++)
                    __builtin_nontemporal_store(
                        oacc[s][mt][r],
                        &op[(size_t)(mt * 16 + quad * 4 + r) * orow + w * 32 + s * 16 + l15]);
        }
    }
}

// ---------------------------------------------------------------------------
// Phase 2: out[M,256] = G[M,256](bf16) @ W_out^T + b_out.  M = 4096*T rows
// (4096 = B rows, baked into the recurrence grid; T read from seqlen so no
// dependence on out_size units).  m = row*T + t matches out's [row][t][col]
// layout exactly.  512 blocks x 512 threads; W_out frags in registers.
// ---------------------------------------------------------------------------
__global__ __launch_bounds__(512, 4)
void out_proj(const short* __restrict__ G, const short* __restrict__ wout_p,
              const float* __restrict__ b_out, const int* __restrict__ seqlen,
              float* __restrict__ out)
{
    __shared__ short abuf[32 * SH];
    const int M    = 4096 * (*seqlen);
    const int tid  = threadIdx.x;
    const int lane = tid & 63;
    const int w    = tid >> 6;
    const int l15  = lane & 15;
    const int quad = lane >> 4;
    const int xr   = tid >> 4;          // 0..31
    const int xc   = (tid & 15) * 16;   // 0..240 (shorts)

    // wave's W_out fragments (cols w*32 .. w*32+31): 2 n-subtiles x 8 kt
    short8 wb[2][8];
    #pragma unroll
    for (int s = 0; s < 2; s++)
        #pragma unroll
        for (int kt = 0; kt < 8; kt++)
            wb[s][kt] = *(const short8*)(wout_p + w * 8192 + kt * 1024 + s * 512 + lane * 8);

    float bo[2] = { b_out[w * 32 + l15], b_out[w * 32 + 16 + l15] };

    for (int ch = blockIdx.x; ch * 32 < M; ch += gridDim.x) {
        const int m0 = ch * 32;
        // stage 32 rows of G -> LDS (coalesced 16B loads)
        const short* gp = G + (size_t)(m0 + xr) * F + xc;
        *(short8*)(abuf + xr * SH + xc)     = *(const short8*)(gp);
        *(short8*)(abuf + xr * SH + xc + 8) = *(const short8*)(gp + 8);
        __syncthreads();

        f32x4 oacc[2][2];
        #pragma unroll
        for (int s = 0; s < 2; s++) { oacc[s][0] = splat4(bo[s]); oacc[s][1] = splat4(bo[s]); }
        #pragma unroll
        for (int kt = 0; kt < 8; kt++) {
            short8 a0 = *(const short8*)(abuf + l15 * SH + kt * 32 + quad * 8);
            short8 a1 = *(const short8*)(abuf + (16 + l15) * SH + kt * 32 + quad * 8);
            #pragma unroll
            for (int s = 0; s < 2; s++) {
                oacc[s][0] = __builtin_amdgcn_mfma_f32_16x16x32_bf16(a0, wb[s][kt], oacc[s][0], 0, 0, 0);
                oacc[s][1] = __builtin_amdgcn_mfma_f32_16x16x32_bf16(a1, wb[s][kt], oacc[s][1], 0, 0, 0);
            }
        }

        float* op = out + (size_t)m0 * F;
        #pragma unroll
        for (int s = 0; s < 2; s++)
          #pragma unroll
          for (int mt = 0; mt < 2; mt++)
            #pragma unroll
            for (int r = 0; r < 4; r++)
                __builtin_nontemporal_store(
                    oacc[s][mt][r],
                    &op[(size_t)(mt * 16 + quad * 4 + r) * F + w * 32 + s * 16 + l15]);
        __syncthreads();   // all waves done reading abuf before next stage
    }
}

extern "C" void kernel_launch(void* const* d_in, const int* in_sizes, int n_in,
                              void* d_out, int out_size, void* d_ws, size_t ws_size,
                              hipStream_t stream)
{
    const float* x    = (const float*)d_in[0];
    const float* Wih  = (const float*)d_in[1];
    const float* Whh  = (const float*)d_in[2];
    const float* bih  = (const float*)d_in[3];
    const float* bhh  = (const float*)d_in[4];
    const float* c0   = (const float*)d_in[5];
    const float* Wout = (const float*)d_in[6];
    const float* bout = (const float*)d_in[7];
    const int* seqlen = (const int*)d_in[8];

    // workspace: packed weights + bf16 h history (G)
    char* ws = (char*)d_ws;
    short* whh_p  = (short*)(ws);                   // 512 KB
    short* wih_hi = (short*)(ws + 512 * 1024);      // 512 KB
    short* wih_lo = (short*)(ws + 1024 * 1024);     // 512 KB
    short* wout_p = (short*)(ws + 1536 * 1024);     // 128 KB
    short* G      = (short*)(ws + 1664 * 1024);     // out_size elems * 2 B (bf16)
    (void)in_sizes; (void)n_in;

    // out_size is in ELEMENTS (fp32): G needs out_size*2 bytes.
    const size_t need = 1664 * 1024 + (size_t)out_size * 2;

    pack_kernel<<<160, 256, 0, stream>>>(Whh, Wih, Wout, whh_p, wih_hi, wih_lo, wout_p);

    if (ws_size >= need) {
        lstm_ker<0><<<128, 512, 0, stream>>>(x, bih, bhh, c0, bout,
                                             whh_p, wih_hi, wih_lo, wout_p,
                                             seqlen, G, (float*)d_out);
        out_proj<<<512, 512, 0, stream>>>(G, wout_p, bout, seqlen, (float*)d_out);
    } else {
        // fallback: R1 fused kernel (workspace too small for h history)
        lstm_ker<1><<<128, 512, 0, stream>>>(x, bih, bhh, c0, bout,
                                             whh_p, wih_hi, wih_lo, wout_p,
                                             seqlen, G, (float*)d_out);
    }
}